// Round 6
// baseline (532.029 us; speedup 1.0000x reference)
//
#include <hip/hip_runtime.h>
#include <cstdint>
#include <cstddef>

#define S_LEN 4096
#define DVEC  1024
#define DH    256

typedef __attribute__((ext_vector_type(8))) short short8;
typedef __attribute__((ext_vector_type(4))) float f32x4;
typedef __attribute__((ext_vector_type(4))) unsigned short ushort4v;
typedef unsigned long long ull;

__device__ __forceinline__ unsigned short f2bf(float f) {
  unsigned u = __builtin_bit_cast(unsigned, f);
  u += 0x7FFFu + ((u >> 16) & 1u);          // round-to-nearest-even
  return (unsigned short)(u >> 16);
}

__device__ __forceinline__ void gl2lds16(const void* g, void* lds) {
  __builtin_amdgcn_global_load_lds(
      (const __attribute__((address_space(1))) unsigned int*)g,
      (__attribute__((address_space(3))) unsigned int*)lds, 16, 0, 0);
}

// ---------------------------------------------------------------------------
// Kernel 0: mask int32[4][4096][4096] -> bits uint64[4][4096][64].
// Pure streaming: wave reads 64 consecutive ints, __ballot -> one uint64.
// 4 words per wave-iteration for MLP.
// ---------------------------------------------------------------------------
__global__ void mcomp_kernel(const int* __restrict__ mask,
                             ull* __restrict__ mbits) {
  const int lane = threadIdx.x & 63;
  const int wid  = (int)((blockIdx.x * blockDim.x + threadIdx.x) >> 6); // 0..4095
  const size_t base = (size_t)wid * 256;   // 256 words per wave
#pragma unroll 4
  for (int i = 0; i < 64; ++i) {
    size_t w0 = base + (size_t)i * 4;
    int v0 = mask[(w0 + 0) * 64 + lane];
    int v1 = mask[(w0 + 1) * 64 + lane];
    int v2 = mask[(w0 + 2) * 64 + lane];
    int v3 = mask[(w0 + 3) * 64 + lane];
    ull b0 = __ballot(v0 != 0);
    ull b1 = __ballot(v1 != 0);
    ull b2 = __ballot(v2 != 0);
    ull b3 = __ballot(v3 != 0);
    if (lane == 0) {
      mbits[w0 + 0] = b0;
      mbits[w0 + 1] = b1;
      mbits[w0 + 2] = b2;
      mbits[w0 + 3] = b3;
    }
  }
}

// ---------------------------------------------------------------------------
// Kernel 1: weights f32 -> bf16 (wq pre-scaled by 1/sqrt(DH)=1/16).
// ---------------------------------------------------------------------------
__global__ void wcvt_kernel(const float* __restrict__ wq,
                            const float* __restrict__ wk,
                            const float* __restrict__ wv,
                            unsigned short* __restrict__ wbf) {
  int t   = blockIdx.x * 256 + threadIdx.x;
  int idx = t * 4;
  int m   = idx >> 18;
  int off = idx & 262143;
  const float* src = (m == 0) ? wq : (m == 1) ? wk : wv;
  float scale = (m == 0) ? 0.0625f : 1.0f;
  f32x4 v = *(const f32x4*)(src + off);
  ushort4v o;
  o.x = f2bf(v.x * scale);
  o.y = f2bf(v.y * scale);
  o.z = f2bf(v.z * scale);
  o.w = f2bf(v.w * scale);
  *(ushort4v*)(wbf + idx) = o;
}

// ---------------------------------------------------------------------------
// Kernel 2: projection GEMM (unchanged). C = x * W^T + b -> bf16; z==2 -> V^T.
// ---------------------------------------------------------------------------
__global__ void proj_kernel(const float* __restrict__ xq,
                            const float* __restrict__ xk,
                            const float* __restrict__ xv,
                            const unsigned short* __restrict__ wbf,
                            const float* __restrict__ bq,
                            const float* __restrict__ bk,
                            const float* __restrict__ bv,
                            unsigned short* __restrict__ qbf,
                            unsigned short* __restrict__ kbf,
                            unsigned short* __restrict__ vtbf) {
  const int tid  = threadIdx.x;
  const int lane = tid & 63;
  const int w    = tid >> 6;
  const int z    = blockIdx.z;
  const int m0   = blockIdx.x * 64;

  const float* x = (z == 0) ? xq : (z == 1) ? xk : xv;
  const unsigned short* wz = wbf + (size_t)z * (DH * DVEC);
  const float* bias = (z == 0) ? bq : (z == 1) ? bk : bv;
  const float bscale = (z == 0) ? 0.0625f : 1.0f;

  __shared__ float At[2][64 * 32];

  f32x4 zero = {0.f, 0.f, 0.f, 0.f};
  f32x4 acc[4][4];
#pragma unroll
  for (int i = 0; i < 4; ++i)
#pragma unroll
    for (int j = 0; j < 4; ++j) acc[i][j] = zero;

  auto stage = [&](int kt, int buf) {
    char* dstb = (char*)&At[buf][0] + w * 2048;
#pragma unroll
    for (int i = 0; i < 2; ++i) {
      int lin  = w * 2048 + i * 1024 + lane * 16;
      int row  = lin >> 7;
      int scol = (lin ^ ((row & 7) << 4)) & 127;
      gl2lds16((const char*)x + ((size_t)(m0 + row) * DVEC + kt * 32) * 4 + scol,
               dstb + i * 1024);
    }
  };

  stage(0, 0);
  __syncthreads();

  for (int kt = 0; kt < 32; ++kt) {
    const int buf = kt & 1;
    if (kt + 1 < 32) stage(kt + 1, buf ^ 1);

    short8 bfr[4];
#pragma unroll
    for (int cf = 0; cf < 4; ++cf) {
      int h = w * 64 + cf * 16 + (lane & 15);
      int d = kt * 32 + (lane >> 4) * 8;
      bfr[cf] = *(const short8*)(wz + (size_t)h * DVEC + d);
    }
    const char* ab = (const char*)&At[buf][0];
#pragma unroll
    for (int rf = 0; rf < 4; ++rf) {
      int row = rf * 16 + (lane & 15);
      int c0  = row * 128 + (lane >> 4) * 32;
      int sw  = (row & 7) << 4;
      f32x4 v0 = *(const f32x4*)(ab + (c0 ^ sw));
      f32x4 v1 = *(const f32x4*)(ab + ((c0 + 16) ^ sw));
      short8 af;
      af[0] = (short)f2bf(v0.x); af[1] = (short)f2bf(v0.y);
      af[2] = (short)f2bf(v0.z); af[3] = (short)f2bf(v0.w);
      af[4] = (short)f2bf(v1.x); af[5] = (short)f2bf(v1.y);
      af[6] = (short)f2bf(v1.z); af[7] = (short)f2bf(v1.w);
#pragma unroll
      for (int cf = 0; cf < 4; ++cf)
        acc[rf][cf] = __builtin_amdgcn_mfma_f32_16x16x32_bf16(af, bfr[cf], acc[rf][cf], 0, 0, 0);
    }
    __syncthreads();
  }

  float bvv[4];
#pragma unroll
  for (int cf = 0; cf < 4; ++cf)
    bvv[cf] = bias[w * 64 + cf * 16 + (lane & 15)] * bscale;

  if (z < 2) {
    unsigned short* o = (z == 0) ? qbf : kbf;
#pragma unroll
    for (int rf = 0; rf < 4; ++rf)
#pragma unroll
      for (int cf = 0; cf < 4; ++cf)
#pragma unroll
        for (int r = 0; r < 4; ++r) {
          int m = m0 + rf * 16 + (lane >> 4) * 4 + r;
          int h = w * 64 + cf * 16 + (lane & 15);
          o[(size_t)m * DH + h] = f2bf(acc[rf][cf][r] + bvv[cf]);
        }
  } else {
    int bb = m0 >> 12;
    int sl = m0 & 4095;
#pragma unroll
    for (int rf = 0; rf < 4; ++rf)
#pragma unroll
      for (int cf = 0; cf < 4; ++cf) {
        int s = sl + rf * 16 + (lane >> 4) * 4;
        int h = w * 64 + cf * 16 + (lane & 15);
        ushort4v o;
        o.x = f2bf(acc[rf][cf][0] + bvv[cf]);
        o.y = f2bf(acc[rf][cf][1] + bvv[cf]);
        o.z = f2bf(acc[rf][cf][2] + bvv[cf]);
        o.w = f2bf(acc[rf][cf][3] + bvv[cf]);
        *(ushort4v*)(vtbf + ((size_t)(bb * DH + h)) * S_LEN + s) = o;
      }
  }
}

// ---------------------------------------------------------------------------
// Kernel 3: fused masked attention. 512 blocks x 512 thr (32 q rows, KVB=64).
// LDS 72KB -> 2 blocks/CU (4 waves/SIMD). All 8 waves symmetric:
//   QK role (kvs = w&3: 16-kv slice, qh = w>>2: 16 q rows)
//   PV role (qs = w>>2: 16 q rows,  hs = w&3: 64 h cols), lag-1 pipelined.
// Per tile t: stageK(t+1) -> gl2lds ; V(t-1) frags -> regs (loaded early,
// hidden under QK) ; QK(t) ; softmax -> P[t&1] ; PV(t-1) from P[(t-1)&1] ;
// ONE barrier. Mask read as precomputed bit-words (uint64 per (q, tile)).
// No online max (scores bounded; exp(0)=1 reproduces reference fill-0).
// ---------------------------------------------------------------------------
__global__ void __launch_bounds__(512, 4)
attn_kernel(const unsigned short* __restrict__ qbf,
            const unsigned short* __restrict__ kbf,
            const unsigned short* __restrict__ vtbf,
            const ull* __restrict__ mbits,
            float* __restrict__ out) {
  const int tid  = threadIdx.x;
  const int lane = tid & 63;
  const int w    = tid >> 6;          // 0..7
  const int j    = lane & 15;
  const int g    = lane >> 4;

  const int kvs = w & 3;              // QK role
  const int qh  = w >> 2;
  const int qs  = w >> 2;             // PV role
  const int hs  = w & 3;

  // XCD-aware decode: 512 blocks, 2 XCDs per batch
  const int bx = blockIdx.x;
  const int x  = bx & 7;
  const int b  = x >> 1;
  const int qt = (bx >> 3) * 2 + (x & 1);   // 0..127
  const int m0 = qt * 32;

  __shared__ char sbuf[73728];
  // K: buf*32768 [0,65536) ; P: 65536 + buf*4096 [65536,73728)
  // lbuf overlays P buf0 (65536) after the loop.

  // ---- Q fragments (16 rows qh*16..): lane j = row, g = k-subchunk
  short8 qreg[8];
  {
    const unsigned short* qrow =
        qbf + ((size_t)(b * S_LEN + m0 + qh * 16 + j)) * DH + g * 8;
#pragma unroll
    for (int kc = 0; kc < 8; ++kc) qreg[kc] = *(const short8*)(qrow + kc * 32);
  }

  f32x4 zero = {0.f, 0.f, 0.f, 0.f};
  f32x4 acc[4];
#pragma unroll
  for (int hf = 0; hf < 4; ++hf) acc[hf] = zero;
  f32x4 lrow = zero;

  // mask-bit base: word index (b*4096 + q)*64 + t, q = m0 + qh*16 + g*4 + r
  const ull* mwb = mbits + ((size_t)(b * S_LEN + m0 + qh * 16 + g * 4)) * 64;
  const int mbit = kvs * 16 + j;

  // ---- K staging: 32 slots of 1KB; slot rid = ks*8 + kc holds (at lane*16)
  //      K[t*64 + ks*16 + j][kc*32 + g*8 .. +8]; wave-uniform LDS dst.
  auto stageK = [&](int t1) {
    const char* src = (const char*)kbf + ((size_t)(b * S_LEN + t1 * 64)) * 512;
    char* dst = sbuf + (t1 & 1) * 32768 + w * 4096;
#pragma unroll
    for (int i = 0; i < 4; ++i) {
      int rid = w * 4 + i;
      int ks  = rid >> 3;
      int kc  = rid & 7;
      gl2lds16(src + (size_t)(ks * 16 + j) * 512 + kc * 64 + g * 16, dst + i * 1024);
    }
  };

  // V fragment pointer for PV role: lane j = h-col
  const unsigned short* vbase =
      vtbf + ((size_t)(b * DH + hs * 64 + j)) * S_LEN;

  // P write base (QK role): chunk (qh*2 + kvs>>1), row' = g*4+r, col byte
  char* const pwb = sbuf + 65536 + (qh * 2 + (kvs >> 1)) * 1024 + ((kvs & 1) * 16 + j) * 2;
  // P read base offset (PV role): chunk (qs*2 + kvc), lane byte j*64 + g*16
  const int proff = (qs * 2) * 1024 + j * 64 + g * 16;

  stageK(0);
  __syncthreads();

  short8 vreg[4][2];   // V(t-1) frags [hf][kvc]

  const int NT = S_LEN / 64;   // 64
  for (int t = 0; t < NT; ++t) {
    if (t + 1 < NT) stageK(t + 1);

    // V(t-1) fragments early (latency hides under QK)
    if (t > 0) {
      const unsigned short* vt = vbase + (t - 1) * 64 + g * 8;
#pragma unroll
      for (int hf = 0; hf < 4; ++hf)
#pragma unroll
        for (int kvc = 0; kvc < 2; ++kvc)
          vreg[hf][kvc] = *(const short8*)(vt + (size_t)(hf * 16) * S_LEN + kvc * 32);
    }

    // mask words for this tile (16 j-lanes share each address; L2-hot 8MB)
    ull mw0 = mwb[0 * 64 + t];
    ull mw1 = mwb[1 * 64 + t];
    ull mw2 = mwb[2 * 64 + t];
    ull mw3 = mwb[3 * 64 + t];

    // ---- QK(t): 2 independent 4-chains
    const char* kb = sbuf + (t & 1) * 32768 + kvs * 8192;
    f32x4 s0 = zero, s1 = zero;
    __builtin_amdgcn_s_setprio(1);
#pragma unroll
    for (int kc = 0; kc < 8; kc += 2) {
      short8 k0 = *(const short8*)(kb + kc * 1024 + lane * 16);
      short8 k1 = *(const short8*)(kb + (kc + 1) * 1024 + lane * 16);
      s0 = __builtin_amdgcn_mfma_f32_16x16x32_bf16(qreg[kc], k0, s0, 0, 0, 0);
      s1 = __builtin_amdgcn_mfma_f32_16x16x32_bf16(qreg[kc + 1], k1, s1, 0, 0, 0);
    }
    __builtin_amdgcn_s_setprio(0);

    // ---- softmax (no max): p = maskbit ? exp(s) : 1 ; store P bf16
    {
      float sv0 = ((mw0 >> mbit) & 1ull) ? (s0[0] + s1[0]) : 0.0f;
      float sv1 = ((mw1 >> mbit) & 1ull) ? (s0[1] + s1[1]) : 0.0f;
      float sv2 = ((mw2 >> mbit) & 1ull) ? (s0[2] + s1[2]) : 0.0f;
      float sv3 = ((mw3 >> mbit) & 1ull) ? (s0[3] + s1[3]) : 0.0f;
      float e0 = __expf(sv0), e1 = __expf(sv1), e2 = __expf(sv2), e3 = __expf(sv3);
      lrow[0] += e0; lrow[1] += e1; lrow[2] += e2; lrow[3] += e3;
      char* pw = pwb + (t & 1) * 4096 + g * 256;
      *(unsigned short*)(pw + 0)   = f2bf(e0);
      *(unsigned short*)(pw + 64)  = f2bf(e1);
      *(unsigned short*)(pw + 128) = f2bf(e2);
      *(unsigned short*)(pw + 192) = f2bf(e3);
    }

    // ---- PV(t-1)
    if (t > 0) {
      const char* pb = sbuf + 65536 + ((t - 1) & 1) * 4096;
      short8 pf0 = *(const short8*)(pb + proff);
      short8 pf1 = *(const short8*)(pb + proff + 1024);
      __builtin_amdgcn_s_setprio(1);
#pragma unroll
      for (int hf = 0; hf < 4; ++hf) {
        acc[hf] = __builtin_amdgcn_mfma_f32_16x16x32_bf16(pf0, vreg[hf][0], acc[hf], 0, 0, 0);
        acc[hf] = __builtin_amdgcn_mfma_f32_16x16x32_bf16(pf1, vreg[hf][1], acc[hf], 0, 0, 0);
      }
      __builtin_amdgcn_s_setprio(0);
    }

    __syncthreads();
  }

  // ---- epilogue: PV(NT-1) (P buf1), l-reduce into lbuf (overlays P buf0)
  {
    const unsigned short* vt = vbase + (NT - 1) * 64 + g * 8;
#pragma unroll
    for (int hf = 0; hf < 4; ++hf)
#pragma unroll
      for (int kvc = 0; kvc < 2; ++kvc)
        vreg[hf][kvc] = *(const short8*)(vt + (size_t)(hf * 16) * S_LEN + kvc * 32);
    const char* pb = sbuf + 65536 + ((NT - 1) & 1) * 4096;
    short8 pf0 = *(const short8*)(pb + proff);
    short8 pf1 = *(const short8*)(pb + proff + 1024);
#pragma unroll
    for (int hf = 0; hf < 4; ++hf) {
      acc[hf] = __builtin_amdgcn_mfma_f32_16x16x32_bf16(pf0, vreg[hf][0], acc[hf], 0, 0, 0);
      acc[hf] = __builtin_amdgcn_mfma_f32_16x16x32_bf16(pf1, vreg[hf][1], acc[hf], 0, 0, 0);
    }
  }

#pragma unroll
  for (int r = 0; r < 4; ++r) {
#pragma unroll
    for (int off = 1; off < 16; off <<= 1)
      lrow[r] += __shfl_xor(lrow[r], off, 64);
  }
  float* lbuf = (float*)(sbuf + 65536);   // [32][4]
  if (j == 0) {
#pragma unroll
    for (int r = 0; r < 4; ++r)
      lbuf[(qh * 16 + g * 4 + r) * 4 + kvs] = lrow[r];
  }
  __syncthreads();

  // ---- normalize + store (PV role rows)
#pragma unroll
  for (int r = 0; r < 4; ++r) {
    int q = qs * 16 + g * 4 + r;
    f32x4 lv = *(const f32x4*)&lbuf[q * 4];
    float linv = 1.0f / (lv[0] + lv[1] + lv[2] + lv[3]);
    float* orow = out + ((size_t)(b * S_LEN + m0 + q)) * DH + hs * 64 + j;
#pragma unroll
    for (int hf = 0; hf < 4; ++hf)
      orow[hf * 16] = acc[hf][r] * linv;
  }
}

// ---------------------------------------------------------------------------
extern "C" void kernel_launch(void* const* d_in, const int* in_sizes, int n_in,
                              void* d_out, int out_size, void* d_ws, size_t ws_size,
                              hipStream_t stream) {
  const float* xq = (const float*)d_in[0];
  const float* xk = (const float*)d_in[1];
  const float* xv = (const float*)d_in[2];
  const int* mask = (const int*)d_in[3];
  const float* wq = (const float*)d_in[4];
  const float* bq = (const float*)d_in[5];
  const float* wk = (const float*)d_in[6];
  const float* bk = (const float*)d_in[7];
  const float* wv = (const float*)d_in[8];
  const float* bv = (const float*)d_in[9];
  float* out = (float*)d_out;

  char* ws = (char*)d_ws;
  unsigned short* wbf  = (unsigned short*)(ws);                    // 1.5 MB
  unsigned short* qbf  = (unsigned short*)(ws + (2ull  << 20));    // 8 MB
  unsigned short* kbf  = (unsigned short*)(ws + (10ull << 20));    // 8 MB
  unsigned short* vtbf = (unsigned short*)(ws + (18ull << 20));    // 8 MB
  ull*            mbit = (ull*)           (ws + (26ull << 20));    // 8 MB

  hipLaunchKernelGGL(mcomp_kernel, dim3(1024), dim3(256), 0, stream, mask, mbit);
  hipLaunchKernelGGL(wcvt_kernel, dim3(768), dim3(256), 0, stream, wq, wk, wv, wbf);
  hipLaunchKernelGGL(proj_kernel, dim3(256, 1, 3), dim3(256), 0, stream,
                     xq, xk, xv, wbf, bq, bk, bv, qbf, kbf, vtbf);
  hipLaunchKernelGGL(attn_kernel, dim3(512), dim3(512), 0, stream,
                     qbf, kbf, vtbf, mbit, out);
}